// Round 2
// baseline (8538.540 us; speedup 1.0000x reference)
//
#include <hip/hip_runtime.h>
#include <cstdint>
#include <cstddef>

#define T_ 64
#define S_ 400
#define B_ 32
#define H_ 512
#define E_ 1024
#define I_ 128

__device__ __forceinline__ float sigmoid_(float x){ return 1.0f/(1.0f + __expf(-x)); }
__device__ __forceinline__ float tanh_(float x){
    float e = __expf(2.0f*fabsf(x));
    float t = 1.0f - 2.0f/(e + 1.0f);
    return copysignf(t, x);
}

// ---------------- one-time kernels ----------------

__global__ __launch_bounds__(256) void init_kernel(const float* __restrict__ init_state,
        const float* __restrict__ init_cov, float* __restrict__ h0, float* __restrict__ cov){
    int i = blockIdx.x*256 + threadIdx.x;
    if (i < B_*H_) h0[i] = init_state[i];
    if (i < B_*S_) cov[i] = init_cov[i];
}

// NOTE: harness reads the whole d_out as float32 — emit index VALUES as floats.
__global__ __launch_bounds__(256) void xidx_kernel(const int* __restrict__ x_index, float* __restrict__ out){
    int i = blockIdx.x*256 + threadIdx.x;
    if (i >= T_*B_*S_) return;
    int s = i % S_;
    int b = (i / S_) % B_;
    out[i] = (float)x_index[s*B_ + b];
}

// Wh_enc[m, f] = sum_k enc[m, k] * W_h[f, k];  m = s*B+b  (M=12800, N=1024, K=1024)
#define BM 64
#define BN 64
#define BK 16
__global__ __launch_bounds__(256) void gemm_whenc(const float* __restrict__ A,
        const float* __restrict__ Bw, float* __restrict__ C){
    __shared__ float As[BK][BM];
    __shared__ float Bs[BK][BN];
    int bm = blockIdx.x;      // 200
    int bn = blockIdx.y;      // 16
    int tid = threadIdx.x;
    int lrow  = tid >> 2;        // 0..63
    int lcol4 = (tid & 3) * 4;   // 0,4,8,12
    int tx = tid & 15, ty = tid >> 4;
    const float* Ab = A  + (size_t)(bm*BM)*1024;
    const float* Bb = Bw + (size_t)(bn*BN)*1024;
    float acc[4][4] = {};
    for (int k0 = 0; k0 < 1024; k0 += BK){
        float4 av = *(const float4*)(Ab + (size_t)lrow*1024 + k0 + lcol4);
        float4 bv = *(const float4*)(Bb + (size_t)lrow*1024 + k0 + lcol4);
        As[lcol4+0][lrow]=av.x; As[lcol4+1][lrow]=av.y; As[lcol4+2][lrow]=av.z; As[lcol4+3][lrow]=av.w;
        Bs[lcol4+0][lrow]=bv.x; Bs[lcol4+1][lrow]=bv.y; Bs[lcol4+2][lrow]=bv.z; Bs[lcol4+3][lrow]=bv.w;
        __syncthreads();
        #pragma unroll
        for (int kk = 0; kk < BK; ++kk){
            float4 a4 = *(const float4*)&As[kk][ty*4];
            float4 b4 = *(const float4*)&Bs[kk][tx*4];
            float a_[4] = {a4.x, a4.y, a4.z, a4.w};
            float b_[4] = {b4.x, b4.y, b4.z, b4.w};
            #pragma unroll
            for (int i=0;i<4;++i)
                #pragma unroll
                for (int j=0;j<4;++j) acc[i][j] = fmaf(a_[i], b_[j], acc[i][j]);
        }
        __syncthreads();
    }
    int m0 = bm*BM + ty*4, n0 = bn*BN + tx*4;
    #pragma unroll
    for (int i=0;i<4;++i){
        float4 o = make_float4(acc[i][0], acc[i][1], acc[i][2], acc[i][3]);
        *(float4*)&C[(size_t)(m0+i)*E_ + n0] = o;
    }
}

// ---------------- per-step kernels ----------------

// GRU1: s1[b,h]. grid (8, 32): 64 h per block, 4 k-parts. block 256.
__global__ __launch_bounds__(256) void gru1_kernel(const float* __restrict__ y,
        const float* __restrict__ hid,
        const float* __restrict__ w_ih, const float* __restrict__ w_hh,
        const float* __restrict__ b_ih, const float* __restrict__ b_hh,
        const float* __restrict__ ymask, float* __restrict__ s1, int t){
    __shared__ float xs[I_];
    __shared__ float hs[H_];
    __shared__ float part[3][64][6];
    int tid = threadIdx.x;
    int b = blockIdx.y;
    int hh = tid & 63, p = tid >> 6;
    int h = blockIdx.x*64 + hh;
    for (int i=tid; i<I_; i+=256) xs[i] = y[(size_t)t*B_*I_ + (size_t)b*I_ + i];
    for (int i=tid; i<H_; i+=256) hs[i] = hid[(size_t)b*H_ + i];
    __syncthreads();
    float gp[6];
    #pragma unroll
    for (int g=0; g<3; ++g){
        const float* wr = w_ih + (size_t)(g*H_ + h)*I_;
        float acc = 0.0f;
        for (int k = p*32; k < p*32 + 32; k += 4){
            float4 w4 = *(const float4*)(wr + k);
            acc = fmaf(w4.x, xs[k+0], acc); acc = fmaf(w4.y, xs[k+1], acc);
            acc = fmaf(w4.z, xs[k+2], acc); acc = fmaf(w4.w, xs[k+3], acc);
        }
        gp[g] = acc;
    }
    #pragma unroll
    for (int g=0; g<3; ++g){
        const float* wr = w_hh + (size_t)(g*H_ + h)*H_;
        float acc = 0.0f;
        for (int k = p*128; k < p*128 + 128; k += 4){
            float4 w4 = *(const float4*)(wr + k);
            acc = fmaf(w4.x, hs[k+0], acc); acc = fmaf(w4.y, hs[k+1], acc);
            acc = fmaf(w4.z, hs[k+2], acc); acc = fmaf(w4.w, hs[k+3], acc);
        }
        gp[3+g] = acc;
    }
    if (p){ 
        #pragma unroll
        for (int j=0;j<6;++j) part[p-1][hh][j] = gp[j]; 
    }
    __syncthreads();
    if (p == 0){
        float gi[3], gh[3];
        #pragma unroll
        for (int j=0;j<3;++j) gi[j] = gp[j]   + part[0][hh][j]   + part[1][hh][j]   + part[2][hh][j]   + b_ih[j*H_ + h];
        #pragma unroll
        for (int j=0;j<3;++j) gh[j] = gp[3+j] + part[0][hh][3+j] + part[1][hh][3+j] + part[2][hh][3+j] + b_hh[j*H_ + h];
        float r = sigmoid_(gi[0] + gh[0]);
        float z = sigmoid_(gi[1] + gh[1]);
        float n = tanh_(gi[2] + r*gh[2]);
        float hv = hs[h];
        float sv = (1.0f - z)*n + z*hv;
        float ym = ymask[t*B_ + b];
        s1[(size_t)b*H_ + h] = ym*sv + (1.0f - ym)*hv;
    }
}

// q[b,f] = s1[b,:] . W_s[f,:] + b_attn[f].  grid (16, 32): 64 f per block, 4 parts.
__global__ __launch_bounds__(256) void qproj_kernel(const float* __restrict__ s1,
        const float* __restrict__ W_s, const float* __restrict__ b_attn, float* __restrict__ qb){
    __shared__ float hs[H_];
    __shared__ float part[3][64];
    int tid = threadIdx.x;
    int b = blockIdx.y;
    int ff = tid & 63, p = tid >> 6;
    int f = blockIdx.x*64 + ff;
    for (int i=tid; i<H_; i+=256) hs[i] = s1[(size_t)b*H_ + i];
    __syncthreads();
    const float* wr = W_s + (size_t)f*H_;
    float acc = 0.0f;
    for (int k = p*128; k < p*128 + 128; k += 4){
        float4 w4 = *(const float4*)(wr + k);
        acc = fmaf(w4.x, hs[k+0], acc); acc = fmaf(w4.y, hs[k+1], acc);
        acc = fmaf(w4.z, hs[k+2], acc); acc = fmaf(w4.w, hs[k+3], acc);
    }
    if (p) part[p-1][ff] = acc;
    __syncthreads();
    if (p == 0) qb[(size_t)b*E_ + f] = acc + part[0][ff] + part[1][ff] + part[2][ff] + b_attn[f];
}

// score[s,b] = xm * sum_e V[e]*tanh(Wh_enc[s,b,e] + qb[b,e] + cov[b,s]*wc[e]); one wave per (s,b)
__global__ __launch_bounds__(256) void score_kernel(const float* __restrict__ whenc,
        const float* __restrict__ qb, const float* __restrict__ cov,
        const float* __restrict__ wc, const float* __restrict__ Vv,
        const float* __restrict__ xmask, float* __restrict__ scores){
    int wave = blockIdx.x*4 + (threadIdx.x >> 6);
    int lane = threadIdx.x & 63;
    int s = wave >> 5, b = wave & 31;
    const float* wp = whenc + (size_t)(s*B_ + b)*E_;
    const float* qp = qb + (size_t)b*E_;
    float cv = cov[b*S_ + s];
    float acc = 0.0f;
    #pragma unroll
    for (int i=0;i<4;++i){
        int e = (i*64 + lane)*4;
        float4 w4 = *(const float4*)(wp + e);
        float4 q4 = *(const float4*)(qp + e);
        float4 c4 = *(const float4*)(wc + e);
        float4 v4 = *(const float4*)(Vv + e);
        acc = fmaf(v4.x, tanh_(w4.x + q4.x + cv*c4.x), acc);
        acc = fmaf(v4.y, tanh_(w4.y + q4.y + cv*c4.y), acc);
        acc = fmaf(v4.z, tanh_(w4.z + q4.z + cv*c4.z), acc);
        acc = fmaf(v4.w, tanh_(w4.w + q4.w + cv*c4.w), acc);
    }
    #pragma unroll
    for (int off=32; off; off>>=1) acc += __shfl_xor(acc, off);
    if (lane == 0){
        float xm = xmask[s*B_ + b];
        scores[s*B_ + b] = (xm == 0.0f) ? -1e9f : acc*xm;
    }
}

// softmax over s per b (redundantly per block), ctx chunk, wa/cov outputs on chunk 0.
// grid 256 = 32 b * 8 chunks of 128 e. block 128.
__global__ __launch_bounds__(128) void attn_ctx_kernel(const float* __restrict__ scores,
        const float* __restrict__ enc, float* __restrict__ cov, float* __restrict__ ctxbuf,
        float* __restrict__ out_ctx, float* __restrict__ out_wa, float* __restrict__ out_cov, int t){
    __shared__ float p[S_];
    __shared__ float red[4];
    int tid = threadIdx.x;
    int b = blockIdx.x >> 3;
    int chunk = blockIdx.x & 7;
    float v[4];
    #pragma unroll
    for (int i=0;i<4;++i){
        int s = tid + i*128;
        v[i] = (s < S_) ? scores[s*B_ + b] : -1e30f;
    }
    float mx = fmaxf(fmaxf(v[0],v[1]), fmaxf(v[2],v[3]));
    #pragma unroll
    for (int off=32; off; off>>=1) mx = fmaxf(mx, __shfl_xor(mx, off));
    if ((tid & 63) == 0) red[tid >> 6] = mx;
    __syncthreads();
    mx = fmaxf(red[0], red[1]);
    float ev[4];
    float sm = 0.0f;
    #pragma unroll
    for (int i=0;i<4;++i){
        int s = tid + i*128;
        ev[i] = (s < S_) ? __expf(v[i] - mx) : 0.0f;
        sm += ev[i];
    }
    #pragma unroll
    for (int off=32; off; off>>=1) sm += __shfl_xor(sm, off);
    if ((tid & 63) == 0) red[2 + (tid >> 6)] = sm;
    __syncthreads();
    float rden = 1.0f/(red[2] + red[3]);
    #pragma unroll
    for (int i=0;i<4;++i){
        int s = tid + i*128;
        if (s < S_) p[s] = ev[i]*rden;
    }
    __syncthreads();
    int e = chunk*128 + tid;
    const float* ep = enc + (size_t)b*E_ + e;
    float acc = 0.0f;
    #pragma unroll 4
    for (int s=0; s<S_; ++s) acc = fmaf(p[s], ep[(size_t)s*(B_*E_)], acc);
    ctxbuf[(size_t)b*E_ + e] = acc;
    out_ctx[(size_t)t*B_*E_ + (size_t)b*E_ + e] = acc;
    if (chunk == 0){
        for (int s=tid; s<S_; s+=128){
            float c = cov[b*S_ + s];
            out_wa [(size_t)t*B_*S_ + (size_t)b*S_ + s] = p[s];
            out_cov[(size_t)t*B_*S_ + (size_t)b*S_ + s] = c;
            cov[b*S_ + s] = c + p[s];
        }
    }
}

// GRU2: s2[b,h] from x=ctx (E), h=s1. grid (8, 32): 64 h per block, 4 parts.
__global__ __launch_bounds__(256) void gru2_kernel(const float* __restrict__ ctx,
        const float* __restrict__ s1,
        const float* __restrict__ w_ih, const float* __restrict__ w_hh,
        const float* __restrict__ b_ih, const float* __restrict__ b_hh,
        const float* __restrict__ ymask, float* __restrict__ hnext,
        float* __restrict__ out_hidden, int t){
    __shared__ float xs[E_];
    __shared__ float hs[H_];
    __shared__ float part[3][64][6];
    int tid = threadIdx.x;
    int b = blockIdx.y;
    int hh = tid & 63, p = tid >> 6;
    int h = blockIdx.x*64 + hh;
    for (int i=tid; i<E_; i+=256) xs[i] = ctx[(size_t)b*E_ + i];
    for (int i=tid; i<H_; i+=256) hs[i] = s1[(size_t)b*H_ + i];
    __syncthreads();
    float gp[6];
    #pragma unroll
    for (int g=0; g<3; ++g){
        const float* wr = w_ih + (size_t)(g*H_ + h)*E_;
        float acc = 0.0f;
        for (int k = p*256; k < p*256 + 256; k += 4){
            float4 w4 = *(const float4*)(wr + k);
            acc = fmaf(w4.x, xs[k+0], acc); acc = fmaf(w4.y, xs[k+1], acc);
            acc = fmaf(w4.z, xs[k+2], acc); acc = fmaf(w4.w, xs[k+3], acc);
        }
        gp[g] = acc;
    }
    #pragma unroll
    for (int g=0; g<3; ++g){
        const float* wr = w_hh + (size_t)(g*H_ + h)*H_;
        float acc = 0.0f;
        for (int k = p*128; k < p*128 + 128; k += 4){
            float4 w4 = *(const float4*)(wr + k);
            acc = fmaf(w4.x, hs[k+0], acc); acc = fmaf(w4.y, hs[k+1], acc);
            acc = fmaf(w4.z, hs[k+2], acc); acc = fmaf(w4.w, hs[k+3], acc);
        }
        gp[3+g] = acc;
    }
    if (p){ 
        #pragma unroll
        for (int j=0;j<6;++j) part[p-1][hh][j] = gp[j]; 
    }
    __syncthreads();
    if (p == 0){
        float gi[3], gh[3];
        #pragma unroll
        for (int j=0;j<3;++j) gi[j] = gp[j]   + part[0][hh][j]   + part[1][hh][j]   + part[2][hh][j]   + b_ih[j*H_ + h];
        #pragma unroll
        for (int j=0;j<3;++j) gh[j] = gp[3+j] + part[0][hh][3+j] + part[1][hh][3+j] + part[2][hh][3+j] + b_hh[j*H_ + h];
        float r = sigmoid_(gi[0] + gh[0]);
        float z = sigmoid_(gi[1] + gh[1]);
        float n = tanh_(gi[2] + r*gh[2]);
        float s1v = hs[h];
        float sv = (1.0f - z)*n + z*s1v;
        float ym = ymask[t*B_ + b];
        float o = ym*sv + (1.0f - ym)*s1v;
        hnext[(size_t)b*H_ + h] = o;
        out_hidden[(size_t)t*B_*H_ + (size_t)b*H_ + h] = o;
    }
}

// ---------------- launch ----------------

extern "C" void kernel_launch(void* const* d_in, const int* in_sizes, int n_in,
                              void* d_out, int out_size, void* d_ws, size_t ws_size,
                              hipStream_t stream) {
    const float* y          = (const float*)d_in[0];
    const float* enc        = (const float*)d_in[1];
    const float* init_state = (const float*)d_in[2];
    const float* xmask      = (const float*)d_in[3];
    const float* ymask      = (const float*)d_in[4];
    const int*   x_index    = (const int*)  d_in[5];
    const float* init_cov   = (const float*)d_in[6];
    const float* W_h        = (const float*)d_in[7];
    const float* W_s        = (const float*)d_in[8];
    const float* W_c        = (const float*)d_in[9];
    const float* b_attn     = (const float*)d_in[10];
    const float* Vv         = (const float*)d_in[11];
    const float* w_ih1      = (const float*)d_in[12];
    const float* w_hh1      = (const float*)d_in[13];
    const float* b_ih1      = (const float*)d_in[14];
    const float* b_hh1      = (const float*)d_in[15];
    const float* w_ih2      = (const float*)d_in[16];
    const float* w_hh2      = (const float*)d_in[17];
    const float* b_ih2      = (const float*)d_in[18];
    const float* b_hh2      = (const float*)d_in[19];

    float* out        = (float*)d_out;
    float* out_hidden = out;                                   // T*B*H
    float* out_ctx    = out_hidden + (size_t)T_*B_*H_;         // T*B*E
    float* out_wa     = out_ctx    + (size_t)T_*B_*E_;         // T*B*S
    float* out_xidx   = out_wa     + (size_t)T_*B_*S_;         // T*B*S (as float values)
    float* out_cov    = out_xidx   + (size_t)T_*B_*S_;         // T*B*S

    float* ws     = (float*)d_ws;
    float* whenc  = ws;                            // S*B*E
    float* qb     = whenc  + (size_t)S_*B_*E_;     // B*E
    float* s1     = qb     + (size_t)B_*E_;        // B*H
    float* h0     = s1     + (size_t)B_*H_;        // B*H
    float* h1     = h0     + (size_t)B_*H_;        // B*H
    float* cov    = h1     + (size_t)B_*H_;        // B*S
    float* scores = cov    + (size_t)B_*S_;        // S*B
    float* ctxbuf = scores + (size_t)S_*B_;        // B*E

    init_kernel<<<64, 256, 0, stream>>>(init_state, init_cov, h0, cov);
    xidx_kernel<<<3200, 256, 0, stream>>>(x_index, out_xidx);
    gemm_whenc<<<dim3(200, 16), 256, 0, stream>>>(enc, W_h, whenc);

    for (int t = 0; t < T_; ++t){
        float* hcur  = (t & 1) ? h1 : h0;
        float* hnext = (t & 1) ? h0 : h1;
        gru1_kernel<<<dim3(8, 32), 256, 0, stream>>>(y, hcur, w_ih1, w_hh1, b_ih1, b_hh1, ymask, s1, t);
        qproj_kernel<<<dim3(16, 32), 256, 0, stream>>>(s1, W_s, b_attn, qb);
        score_kernel<<<3200, 256, 0, stream>>>(whenc, qb, cov, W_c, Vv, xmask, scores);
        attn_ctx_kernel<<<256, 128, 0, stream>>>(scores, enc, cov, ctxbuf, out_ctx, out_wa, out_cov, t);
        gru2_kernel<<<dim3(8, 32), 256, 0, stream>>>(ctxbuf, s1, w_ih2, w_hh2, b_ih2, b_hh2, ymask, hnext, out_hidden, t);
    }
}

// Round 3
// 7281.181 us; speedup vs baseline: 1.1727x; 1.1727x over previous
//
#include <hip/hip_runtime.h>
#include <cstdint>
#include <cstddef>

#define T_ 64
#define S_ 400
#define B_ 32
#define H_ 512
#define E_ 1024
#define I_ 128

__device__ __forceinline__ float sigmoid_(float x){ return 1.0f/(1.0f + __expf(-x)); }
__device__ __forceinline__ float tanh_(float x){
    float e = __expf(2.0f*fabsf(x));
    float t = 1.0f - 2.0f/(e + 1.0f);
    return copysignf(t, x);
}

// ---------------- one-time kernels ----------------

__global__ __launch_bounds__(256) void init_kernel(const float* __restrict__ init_state,
        const float* __restrict__ init_cov, float* __restrict__ h0, float* __restrict__ cov){
    int i = blockIdx.x*256 + threadIdx.x;
    if (i < B_*H_) h0[i] = init_state[i];
    if (i < B_*S_) cov[i] = init_cov[i];
}

// harness reads whole d_out as float32 — emit index VALUES as floats.
__global__ __launch_bounds__(256) void xidx_kernel(const int* __restrict__ x_index, float* __restrict__ out){
    int i = blockIdx.x*256 + threadIdx.x;
    if (i >= T_*B_*S_) return;
    int s = i % S_;
    int b = (i / S_) % B_;
    out[i] = (float)x_index[s*B_ + b];
}

// Wh_enc[m, f] = sum_k enc[m, k] * W_h[f, k];  m = s*B+b  (M=12800, N=1024, K=1024)
#define BM 64
#define BN 64
#define BK 16
__global__ __launch_bounds__(256) void gemm_whenc(const float* __restrict__ A,
        const float* __restrict__ Bw, float* __restrict__ C){
    __shared__ float As[BK][BM];
    __shared__ float Bs[BK][BN];
    int bm = blockIdx.x;      // 200
    int bn = blockIdx.y;      // 16
    int tid = threadIdx.x;
    int lrow  = tid >> 2;        // 0..63
    int lcol4 = (tid & 3) * 4;   // 0,4,8,12
    int tx = tid & 15, ty = tid >> 4;
    const float* Ab = A  + (size_t)(bm*BM)*1024;
    const float* Bb = Bw + (size_t)(bn*BN)*1024;
    float acc[4][4] = {};
    for (int k0 = 0; k0 < 1024; k0 += BK){
        float4 av = *(const float4*)(Ab + (size_t)lrow*1024 + k0 + lcol4);
        float4 bv = *(const float4*)(Bb + (size_t)lrow*1024 + k0 + lcol4);
        As[lcol4+0][lrow]=av.x; As[lcol4+1][lrow]=av.y; As[lcol4+2][lrow]=av.z; As[lcol4+3][lrow]=av.w;
        Bs[lcol4+0][lrow]=bv.x; Bs[lcol4+1][lrow]=bv.y; Bs[lcol4+2][lrow]=bv.z; Bs[lcol4+3][lrow]=bv.w;
        __syncthreads();
        #pragma unroll
        for (int kk = 0; kk < BK; ++kk){
            float4 a4 = *(const float4*)&As[kk][ty*4];
            float4 b4 = *(const float4*)&Bs[kk][tx*4];
            float a_[4] = {a4.x, a4.y, a4.z, a4.w};
            float b_[4] = {b4.x, b4.y, b4.z, b4.w};
            #pragma unroll
            for (int i=0;i<4;++i)
                #pragma unroll
                for (int j=0;j<4;++j) acc[i][j] = fmaf(a_[i], b_[j], acc[i][j]);
        }
        __syncthreads();
    }
    int m0 = bm*BM + ty*4, n0 = bn*BN + tx*4;
    #pragma unroll
    for (int i=0;i<4;++i){
        float4 o = make_float4(acc[i][0], acc[i][1], acc[i][2], acc[i][3]);
        *(float4*)&C[(size_t)(m0+i)*E_ + n0] = o;
    }
}

// ---------------- per-step kernels ----------------

// GRU1: s1[b,h]. grid (8, 32): 64 h per block, 4 k-parts. block 256.
__global__ __launch_bounds__(256) void gru1_kernel(const float* __restrict__ y,
        const float* __restrict__ hid,
        const float* __restrict__ w_ih, const float* __restrict__ w_hh,
        const float* __restrict__ b_ih, const float* __restrict__ b_hh,
        const float* __restrict__ ymask, float* __restrict__ s1, int t){
    __shared__ float xs[I_];
    __shared__ float hs[H_];
    __shared__ float part[3][64][6];
    int tid = threadIdx.x;
    int b = blockIdx.y;
    int hh = tid & 63, p = tid >> 6;
    int h = blockIdx.x*64 + hh;
    for (int i=tid; i<I_; i+=256) xs[i] = y[(size_t)t*B_*I_ + (size_t)b*I_ + i];
    for (int i=tid; i<H_; i+=256) hs[i] = hid[(size_t)b*H_ + i];
    __syncthreads();
    float gp[6];
    #pragma unroll
    for (int g=0; g<3; ++g){
        const float* wr = w_ih + (size_t)(g*H_ + h)*I_;
        float acc = 0.0f;
        for (int k = p*32; k < p*32 + 32; k += 4){
            float4 w4 = *(const float4*)(wr + k);
            acc = fmaf(w4.x, xs[k+0], acc); acc = fmaf(w4.y, xs[k+1], acc);
            acc = fmaf(w4.z, xs[k+2], acc); acc = fmaf(w4.w, xs[k+3], acc);
        }
        gp[g] = acc;
    }
    #pragma unroll
    for (int g=0; g<3; ++g){
        const float* wr = w_hh + (size_t)(g*H_ + h)*H_;
        float acc = 0.0f;
        for (int k = p*128; k < p*128 + 128; k += 4){
            float4 w4 = *(const float4*)(wr + k);
            acc = fmaf(w4.x, hs[k+0], acc); acc = fmaf(w4.y, hs[k+1], acc);
            acc = fmaf(w4.z, hs[k+2], acc); acc = fmaf(w4.w, hs[k+3], acc);
        }
        gp[3+g] = acc;
    }
    if (p){ 
        #pragma unroll
        for (int j=0;j<6;++j) part[p-1][hh][j] = gp[j]; 
    }
    __syncthreads();
    if (p == 0){
        float gi[3], gh[3];
        #pragma unroll
        for (int j=0;j<3;++j) gi[j] = gp[j]   + part[0][hh][j]   + part[1][hh][j]   + part[2][hh][j]   + b_ih[j*H_ + h];
        #pragma unroll
        for (int j=0;j<3;++j) gh[j] = gp[3+j] + part[0][hh][3+j] + part[1][hh][3+j] + part[2][hh][3+j] + b_hh[j*H_ + h];
        float r = sigmoid_(gi[0] + gh[0]);
        float z = sigmoid_(gi[1] + gh[1]);
        float n = tanh_(gi[2] + r*gh[2]);
        float hv = hs[h];
        float sv = (1.0f - z)*n + z*hv;
        float ym = ymask[t*B_ + b];
        s1[(size_t)b*H_ + h] = ym*sv + (1.0f - ym)*hv;
    }
}

// q[b,f] = s1[b,:] . W_s[f,:] + b_attn[f].  grid (16, 32): 64 f per block, 4 parts.
__global__ __launch_bounds__(256) void qproj_kernel(const float* __restrict__ s1,
        const float* __restrict__ W_s, const float* __restrict__ b_attn, float* __restrict__ qb){
    __shared__ float hs[H_];
    __shared__ float part[3][64];
    int tid = threadIdx.x;
    int b = blockIdx.y;
    int ff = tid & 63, p = tid >> 6;
    int f = blockIdx.x*64 + ff;
    for (int i=tid; i<H_; i+=256) hs[i] = s1[(size_t)b*H_ + i];
    __syncthreads();
    const float* wr = W_s + (size_t)f*H_;
    float acc = 0.0f;
    for (int k = p*128; k < p*128 + 128; k += 4){
        float4 w4 = *(const float4*)(wr + k);
        acc = fmaf(w4.x, hs[k+0], acc); acc = fmaf(w4.y, hs[k+1], acc);
        acc = fmaf(w4.z, hs[k+2], acc); acc = fmaf(w4.w, hs[k+3], acc);
    }
    if (p) part[p-1][ff] = acc;
    __syncthreads();
    if (p == 0) qb[(size_t)b*E_ + f] = acc + part[0][ff] + part[1][ff] + part[2][ff] + b_attn[f];
}

// score_t[b,s] = xm * sum_e V[e]*tanh(Wh_enc[s,b,e] + qb[b,e] + cov[b,s]*wc[e]); one wave per (s,b)
__global__ __launch_bounds__(256) void score_kernel(const float* __restrict__ whenc,
        const float* __restrict__ qb, const float* __restrict__ cov,
        const float* __restrict__ wc, const float* __restrict__ Vv,
        const float* __restrict__ xmask, float* __restrict__ scores_t){
    int wave = blockIdx.x*4 + (threadIdx.x >> 6);
    int lane = threadIdx.x & 63;
    int s = wave >> 5, b = wave & 31;
    const float* wp = whenc + (size_t)(s*B_ + b)*E_;
    const float* qp = qb + (size_t)b*E_;
    float cv = cov[b*S_ + s];
    float acc = 0.0f;
    #pragma unroll
    for (int i=0;i<4;++i){
        int e = (i*64 + lane)*4;
        float4 w4 = *(const float4*)(wp + e);
        float4 q4 = *(const float4*)(qp + e);
        float4 c4 = *(const float4*)(wc + e);
        float4 v4 = *(const float4*)(Vv + e);
        acc = fmaf(v4.x, tanh_(w4.x + q4.x + cv*c4.x), acc);
        acc = fmaf(v4.y, tanh_(w4.y + q4.y + cv*c4.y), acc);
        acc = fmaf(v4.z, tanh_(w4.z + q4.z + cv*c4.z), acc);
        acc = fmaf(v4.w, tanh_(w4.w + q4.w + cv*c4.w), acc);
    }
    #pragma unroll
    for (int off=32; off; off>>=1) acc += __shfl_xor(acc, off);
    if (lane == 0){
        float xm = xmask[s*B_ + b];
        scores_t[b*S_ + s] = (xm == 0.0f) ? -1e9f : acc*xm;
    }
}

// softmax (redundant per block, coalesced from scores_t) + coalesced ctx reduction.
// grid (16 e-groups of 64, 32 b). block 256 = 4 waves; wave w reduces s-slice [w*100, w*100+100).
__global__ __launch_bounds__(256) void ctx_kernel(const float* __restrict__ scores_t,
        const float* __restrict__ enc, float* __restrict__ cov, float* __restrict__ ctxbuf,
        float* __restrict__ out_ctx, float* __restrict__ out_wa, float* __restrict__ out_cov, int t){
    __shared__ float p[S_];
    __shared__ float sacc[4][64];
    __shared__ float red[8];
    int tid = threadIdx.x;
    int b  = blockIdx.y;
    int e0 = blockIdx.x * 64;
    // ---- softmax over s (block-redundant) ----
    float v0 = scores_t[b*S_ + tid];                                   // tid < 256 < 400
    float v1 = (tid + 256 < S_) ? scores_t[b*S_ + tid + 256] : -1e30f;
    float mx = fmaxf(v0, v1);
    #pragma unroll
    for (int off=32; off; off>>=1) mx = fmaxf(mx, __shfl_xor(mx, off));
    int wid = tid >> 6, lane = tid & 63;
    if (lane == 0) red[wid] = mx;
    __syncthreads();
    mx = fmaxf(fmaxf(red[0], red[1]), fmaxf(red[2], red[3]));
    float e0v = __expf(v0 - mx);
    float e1v = (tid + 256 < S_) ? __expf(v1 - mx) : 0.0f;
    float sm = e0v + e1v;
    #pragma unroll
    for (int off=32; off; off>>=1) sm += __shfl_xor(sm, off);
    if (lane == 0) red[4 + wid] = sm;
    __syncthreads();
    float rden = 1.0f/(red[4] + red[5] + red[6] + red[7]);
    p[tid] = e0v * rden;
    if (tid + 256 < S_) p[tid + 256] = e1v * rden;
    __syncthreads();
    // ---- ctx reduction: wave w covers s in [w*100, w*100+100), lane = e offset ----
    const float* ep = enc + (size_t)b*E_ + e0 + lane;
    float acc = 0.0f;
    int sbeg = wid*100, send = sbeg + 100;
    #pragma unroll 4
    for (int s = sbeg; s < send; ++s)
        acc = fmaf(p[s], ep[(size_t)s*(B_*E_)], acc);
    sacc[wid][lane] = acc;
    __syncthreads();
    if (wid == 0){
        float a = sacc[0][lane] + sacc[1][lane] + sacc[2][lane] + sacc[3][lane];
        int e = e0 + lane;
        ctxbuf[(size_t)b*E_ + e] = a;
        out_ctx[(size_t)t*B_*E_ + (size_t)b*E_ + e] = a;
    }
    // ---- wa / coverage outputs (one block per b) ----
    if (blockIdx.x == 0){
        for (int s = tid; s < S_; s += 256){
            float c = cov[b*S_ + s];
            out_wa [(size_t)t*B_*S_ + (size_t)b*S_ + s] = p[s];
            out_cov[(size_t)t*B_*S_ + (size_t)b*S_ + s] = c;
            cov[b*S_ + s] = c + p[s];
        }
    }
}

// GRU2: s2[b,h] from x=ctx (E), h=s1. grid (8, 32): 64 h per block, 4 parts.
__global__ __launch_bounds__(256) void gru2_kernel(const float* __restrict__ ctx,
        const float* __restrict__ s1,
        const float* __restrict__ w_ih, const float* __restrict__ w_hh,
        const float* __restrict__ b_ih, const float* __restrict__ b_hh,
        const float* __restrict__ ymask, float* __restrict__ hnext,
        float* __restrict__ out_hidden, int t){
    __shared__ float xs[E_];
    __shared__ float hs[H_];
    __shared__ float part[3][64][6];
    int tid = threadIdx.x;
    int b = blockIdx.y;
    int hh = tid & 63, p = tid >> 6;
    int h = blockIdx.x*64 + hh;
    for (int i=tid; i<E_; i+=256) xs[i] = ctx[(size_t)b*E_ + i];
    for (int i=tid; i<H_; i+=256) hs[i] = s1[(size_t)b*H_ + i];
    __syncthreads();
    float gp[6];
    #pragma unroll
    for (int g=0; g<3; ++g){
        const float* wr = w_ih + (size_t)(g*H_ + h)*E_;
        float acc = 0.0f;
        for (int k = p*256; k < p*256 + 256; k += 4){
            float4 w4 = *(const float4*)(wr + k);
            acc = fmaf(w4.x, xs[k+0], acc); acc = fmaf(w4.y, xs[k+1], acc);
            acc = fmaf(w4.z, xs[k+2], acc); acc = fmaf(w4.w, xs[k+3], acc);
        }
        gp[g] = acc;
    }
    #pragma unroll
    for (int g=0; g<3; ++g){
        const float* wr = w_hh + (size_t)(g*H_ + h)*H_;
        float acc = 0.0f;
        for (int k = p*128; k < p*128 + 128; k += 4){
            float4 w4 = *(const float4*)(wr + k);
            acc = fmaf(w4.x, hs[k+0], acc); acc = fmaf(w4.y, hs[k+1], acc);
            acc = fmaf(w4.z, hs[k+2], acc); acc = fmaf(w4.w, hs[k+3], acc);
        }
        gp[3+g] = acc;
    }
    if (p){ 
        #pragma unroll
        for (int j=0;j<6;++j) part[p-1][hh][j] = gp[j]; 
    }
    __syncthreads();
    if (p == 0){
        float gi[3], gh[3];
        #pragma unroll
        for (int j=0;j<3;++j) gi[j] = gp[j]   + part[0][hh][j]   + part[1][hh][j]   + part[2][hh][j]   + b_ih[j*H_ + h];
        #pragma unroll
        for (int j=0;j<3;++j) gh[j] = gp[3+j] + part[0][hh][3+j] + part[1][hh][3+j] + part[2][hh][3+j] + b_hh[j*H_ + h];
        float r = sigmoid_(gi[0] + gh[0]);
        float z = sigmoid_(gi[1] + gh[1]);
        float n = tanh_(gi[2] + r*gh[2]);
        float s1v = hs[h];
        float sv = (1.0f - z)*n + z*s1v;
        float ym = ymask[t*B_ + b];
        float o = ym*sv + (1.0f - ym)*s1v;
        hnext[(size_t)b*H_ + h] = o;
        out_hidden[(size_t)t*B_*H_ + (size_t)b*H_ + h] = o;
    }
}

// ---------------- launch ----------------

extern "C" void kernel_launch(void* const* d_in, const int* in_sizes, int n_in,
                              void* d_out, int out_size, void* d_ws, size_t ws_size,
                              hipStream_t stream) {
    const float* y          = (const float*)d_in[0];
    const float* enc        = (const float*)d_in[1];
    const float* init_state = (const float*)d_in[2];
    const float* xmask      = (const float*)d_in[3];
    const float* ymask      = (const float*)d_in[4];
    const int*   x_index    = (const int*)  d_in[5];
    const float* init_cov   = (const float*)d_in[6];
    const float* W_h        = (const float*)d_in[7];
    const float* W_s        = (const float*)d_in[8];
    const float* W_c        = (const float*)d_in[9];
    const float* b_attn     = (const float*)d_in[10];
    const float* Vv         = (const float*)d_in[11];
    const float* w_ih1      = (const float*)d_in[12];
    const float* w_hh1      = (const float*)d_in[13];
    const float* b_ih1      = (const float*)d_in[14];
    const float* b_hh1      = (const float*)d_in[15];
    const float* w_ih2      = (const float*)d_in[16];
    const float* w_hh2      = (const float*)d_in[17];
    const float* b_ih2      = (const float*)d_in[18];
    const float* b_hh2      = (const float*)d_in[19];

    float* out        = (float*)d_out;
    float* out_hidden = out;                                   // T*B*H
    float* out_ctx    = out_hidden + (size_t)T_*B_*H_;         // T*B*E
    float* out_wa     = out_ctx    + (size_t)T_*B_*E_;         // T*B*S
    float* out_xidx   = out_wa     + (size_t)T_*B_*S_;         // T*B*S (as float values)
    float* out_cov    = out_xidx   + (size_t)T_*B_*S_;         // T*B*S

    float* ws     = (float*)d_ws;
    float* whenc  = ws;                            // S*B*E
    float* qb     = whenc  + (size_t)S_*B_*E_;     // B*E
    float* s1     = qb     + (size_t)B_*E_;        // B*H
    float* h0     = s1     + (size_t)B_*H_;        // B*H
    float* h1     = h0     + (size_t)B_*H_;        // B*H
    float* cov    = h1     + (size_t)B_*H_;        // B*S
    float* scores = cov    + (size_t)B_*S_;        // B*S (transposed: [b][s])
    float* ctxbuf = scores + (size_t)B_*S_;        // B*E

    init_kernel<<<64, 256, 0, stream>>>(init_state, init_cov, h0, cov);
    xidx_kernel<<<3200, 256, 0, stream>>>(x_index, out_xidx);
    gemm_whenc<<<dim3(200, 16), 256, 0, stream>>>(enc, W_h, whenc);

    for (int t = 0; t < T_; ++t){
        float* hcur  = (t & 1) ? h1 : h0;
        float* hnext = (t & 1) ? h0 : h1;
        gru1_kernel<<<dim3(8, 32), 256, 0, stream>>>(y, hcur, w_ih1, w_hh1, b_ih1, b_hh1, ymask, s1, t);
        qproj_kernel<<<dim3(16, 32), 256, 0, stream>>>(s1, W_s, b_attn, qb);
        score_kernel<<<3200, 256, 0, stream>>>(whenc, qb, cov, W_c, Vv, xmask, scores);
        ctx_kernel<<<dim3(16, 32), 256, 0, stream>>>(scores, enc, cov, ctxbuf, out_ctx, out_wa, out_cov, t);
        gru2_kernel<<<dim3(8, 32), 256, 0, stream>>>(ctxbuf, s1, w_ih2, w_hh2, b_ih2, b_hh2, ymask, hnext, out_hidden, t);
    }
}